// Round 4
// baseline (45288.037 us; speedup 1.0000x reference)
//
#include <hip/hip_runtime.h>
#include <hip/hip_cooperative_groups.h>
#include <stdint.h>

#define T_FRAMES 1500
#define B_BATCH  32
#define E_DIM    512
#define H_DIM    512
#define NCLS     31
#define L_STEPS  101
#define EOS_TOK  30
#define NBLK     256
#define NTHR     1024
#define NSLICE   8
#define TSLICE   188          // ceil(1500/8)
#define ROWS_A   12           // 16 waves * 12 = 192 >= 188

typedef unsigned short ushort_t;
typedef ushort_t ushort8_t __attribute__((ext_vector_type(8)));

__device__ __forceinline__ float bf2f(ushort_t u) {
    union { unsigned int i; float f; } v; v.i = ((unsigned int)u) << 16; return v.f;
}
__device__ __forceinline__ ushort_t f2bf(float f) {
    union { float f; unsigned int i; } v; v.f = f;
    unsigned int r = v.i + 0x7FFFu + ((v.i >> 16) & 1u);
    return (ushort_t)(r >> 16);
}
__device__ __forceinline__ float wave_sum(float v) {
    #pragma unroll
    for (int o = 32; o > 0; o >>= 1) v += __shfl_xor(v, o, 64);
    return v;
}
template<int N>
__device__ __forceinline__ void wave_sum_n(float* v) {
    #pragma unroll
    for (int o = 32; o > 0; o >>= 1) {
        #pragma unroll
        for (int i = 0; i < N; ++i) v[i] += __shfl_xor(v[i], o, 64);
    }
}
__device__ __forceinline__ float tanh_f(float x) {
    float e = __expf(2.0f * x);
    return 1.0f - 2.0f * __builtin_amdgcn_rcpf(e + 1.0f);
}
__device__ __forceinline__ float sigmoid_f(float x) {
    return __builtin_amdgcn_rcpf(1.0f + __expf(-x));
}

// per-group (8-block) barrier: per-block flag on its own 128B line.
// arrive: release store (agent). wait: relaxed agent spin loads. then threadfence.
__device__ __forceinline__ void group_barrier(int* flags, int b, int s, int k, int tid) {
    __syncthreads();
    if (tid == 0)
        __hip_atomic_store(&flags[(b * NSLICE + s) * 32], k,
                           __ATOMIC_RELEASE, __HIP_MEMORY_SCOPE_AGENT);
    if (tid < NSLICE) {
        while (__hip_atomic_load(&flags[(b * NSLICE + tid) * 32],
                                 __ATOMIC_RELAXED, __HIP_MEMORY_SCOPE_AGENT) < k) { }
    }
    __syncthreads();
    __threadfence();   // acquire: invalidate stale L1/L2 before reading remote data
}

// ---------------- init: texts2, h-state, loss acc, barrier flags ----------------
__global__ __launch_bounds__(256) void init_kernel(
    const int* __restrict__ texts, const int* __restrict__ text_lens,
    const float* __restrict__ h0p,
    int* __restrict__ texts2, float* __restrict__ h0buf, float* __restrict__ h1buf,
    float* __restrict__ acc, int* __restrict__ flags)
{
    int idx = blockIdx.x * 256 + threadIdx.x;
    if (idx < 2) acc[idx] = 0.f;
    if (idx < B_BATCH * NSLICE * 32) flags[idx] = 0;
    if (idx < B_BATCH * L_STEPS) {
        int b = idx / L_STEPS, j = idx % L_STEPS;
        int v = (j < 100) ? texts[b * 100 + j] : 0;
        if (j == text_lens[b]) v = EOS_TOK;
        texts2[idx] = v;
    }
    for (int i = idx; i < B_BATCH * H_DIM; i += gridDim.x * 256) {
        h0buf[i] = h0p[i & (H_DIM - 1)];
        h1buf[i] = h0p[H_DIM + (i & (H_DIM - 1))];
    }
}

// ---------------- one-time f32 -> bf16 convert (no transpose) ----------------
__global__ __launch_bounds__(256) void cvt_kernel(const float* __restrict__ in,
                                                  ushort_t* __restrict__ out, int n) {
    int i = (blockIdx.x * 256 + threadIdx.x) * 8;
    if (i >= n) return;
    float4 a = *(const float4*)(in + i);
    float4 b = *(const float4*)(in + i + 4);
    ushort8_t o;
    o[0] = f2bf(a.x); o[1] = f2bf(a.y); o[2] = f2bf(a.z); o[3] = f2bf(a.w);
    o[4] = f2bf(b.x); o[5] = f2bf(b.y); o[6] = f2bf(b.z); o[7] = f2bf(b.w);
    *(ushort8_t*)(out + i) = o;
}

// ---------------- encoded [t][b][e] f32 -> encBt [b][t][e] bf16 ----------------
__global__ __launch_bounds__(64) void cvt_transpose_kernel(const float* __restrict__ in,
                                                           ushort_t* __restrict__ out) {
    int row = blockIdx.x;                 // 0 .. T*B-1, row = t*32+b
    int t = row >> 5, b = row & 31;
    int k = threadIdx.x * 8;
    const float* ip = in + (size_t)row * E_DIM + k;
    float4 a = *(const float4*)(ip);
    float4 c = *(const float4*)(ip + 4);
    ushort8_t o;
    o[0] = f2bf(a.x); o[1] = f2bf(a.y); o[2] = f2bf(a.z); o[3] = f2bf(a.w);
    o[4] = f2bf(c.x); o[5] = f2bf(c.y); o[6] = f2bf(c.z); o[7] = f2bf(c.w);
    *(ushort8_t*)(out + ((size_t)b * T_FRAMES + t) * E_DIM + k) = o;
}

// ---------------- enc_contrib GEMM (f32 in, bf16 out, batch-major C) ----------------
#define GTM 128
#define GTN 128
#define GTK 32
#define GLDA (GTM + 4)

__global__ __launch_bounds__(256) void enc_gemm_kernel(
    const float* __restrict__ A, const float* __restrict__ W,
    const float* __restrict__ bias, ushort_t* __restrict__ C)
{
    __shared__ float As[GTK][GLDA];
    __shared__ float Bs[GTK][GLDA];
    const int m0 = blockIdx.y * GTM;
    const int n0 = blockIdx.x * GTN;
    const int tid = threadIdx.x;
    const int tx = tid & 15, ty = tid >> 4;
    const int lr = tid >> 3;
    const int lc = (tid & 7) << 2;
    float acc[8][8] = {};
    for (int k0 = 0; k0 < E_DIM; k0 += GTK) {
        #pragma unroll
        for (int p = 0; p < 4; ++p) {
            float4 a = *(const float4*)(A + (size_t)(m0 + lr + 32 * p) * E_DIM + k0 + lc);
            As[lc + 0][lr + 32 * p] = a.x; As[lc + 1][lr + 32 * p] = a.y;
            As[lc + 2][lr + 32 * p] = a.z; As[lc + 3][lr + 32 * p] = a.w;
            float4 b = *(const float4*)(W + (size_t)(n0 + lr + 32 * p) * E_DIM + k0 + lc);
            Bs[lc + 0][lr + 32 * p] = b.x; Bs[lc + 1][lr + 32 * p] = b.y;
            Bs[lc + 2][lr + 32 * p] = b.z; Bs[lc + 3][lr + 32 * p] = b.w;
        }
        __syncthreads();
        #pragma unroll
        for (int k = 0; k < GTK; ++k) {
            float av[8], bv[8];
            *(float4*)&av[0] = *(const float4*)&As[k][ty * 8];
            *(float4*)&av[4] = *(const float4*)&As[k][ty * 8 + 4];
            *(float4*)&bv[0] = *(const float4*)&Bs[k][tx * 8];
            *(float4*)&bv[4] = *(const float4*)&Bs[k][tx * 8 + 4];
            #pragma unroll
            for (int i = 0; i < 8; ++i)
                #pragma unroll
                for (int j = 0; j < 8; ++j)
                    acc[i][j] = fmaf(av[i], bv[j], acc[i][j]);
        }
        __syncthreads();
    }
    const float* bp = bias + n0 + tx * 8;
    #pragma unroll
    for (int i = 0; i < 8; ++i) {
        int m = m0 + ty * 8 + i;
        int b = m & 31, t = m >> 5;       // A rows are t*32+b
        ushort8_t o;
        #pragma unroll
        for (int j = 0; j < 8; ++j) o[j] = f2bf(acc[i][j] + bp[j]);
        *(ushort8_t*)(C + ((size_t)b * T_FRAMES + t) * H_DIM + n0 + tx * 8) = o;
    }
}

// ---------------- persistent decoder: 8 blocks per batch, custom barriers ----------------
struct Params {
    const float* encoded; const int* lens; const float* emb;
    const float* w_score; const float* b_score;
    const float* b_ih0; const float* b_hh0; const float* b_ih1; const float* b_hh1;
    const ushort_t* ec; const ushort_t* encBt;
    const ushort_t* Wrec; const ushort_t* Wih0; const ushort_t* Whh0;
    const ushort_t* Wih1; const ushort_t* Whh1;
    float* rec; float* ctxPart; float* denomPart;
    float* h0a; float* h0b; float* h1a; float* h1b;
    float* outputs; const int* texts2; int* flags;
    int useEncB;
};

__global__ __launch_bounds__(NTHR, 1) void decoder_kernel(Params p) {
    const int tid = threadIdx.x;          // 0..1023
    const int bid = blockIdx.x;           // 0..255
    const int lane = tid & 63;
    const int wsub = tid >> 6;            // 0..15
    const int b = bid >> 3;               // batch
    const int s = bid & 7;                // slice (maps to XCD s under round-robin)
    __shared__ float sctx[16][E_DIM];     // 32 KB
    __shared__ float sred[32];

    // ---- initial rec slice from h0a ----
    {
        const float* x = p.h0a + b * H_DIM + lane * 8;
        float x8[8];
        *(float4*)&x8[0] = *(const float4*)(x);
        *(float4*)&x8[4] = *(const float4*)(x + 4);
        #pragma unroll
        for (int i = 0; i < 4; ++i) {
            int h = s * 64 + wsub * 4 + i;
            ushort8_t w8 = *(const ushort8_t*)(p.Wrec + (size_t)h * H_DIM + lane * 8);
            float v = 0.f;
            #pragma unroll
            for (int j = 0; j < 8; ++j) v = fmaf(x8[j], bf2f(w8[j]), v);
            v = wave_sum(v);
            if (lane == 0) p.rec[b * H_DIM + h] = v;
        }
    }
    group_barrier(p.flags, b, s, 1, tid);

    const int len = p.lens[b];
    for (int l = 0; l < L_STEPS; ++l) {
        const float* h0cur = (l & 1) ? p.h0b : p.h0a;
        float*       h0nxt = (l & 1) ? p.h0a : p.h0b;
        const float* h1cur = (l & 1) ? p.h1b : p.h1a;
        float*       h1nxt = (l & 1) ? p.h1a : p.h1b;

        // ---- phase A: scores + exp + context/denom partials for t-slice s ----
        {
            int tA = s * TSLICE + wsub * ROWS_A;
            int tEnd = min(min(s * TSLICE + TSLICE, len), tA + ROWS_A);
            float rec8[8], w8[8];
            const float* rp = p.rec + b * H_DIM + lane * 8;
            *(float4*)&rec8[0] = *(const float4*)(rp);
            *(float4*)&rec8[4] = *(const float4*)(rp + 4);
            const float* wp = p.w_score + lane * 8;
            *(float4*)&w8[0] = *(const float4*)(wp);
            *(float4*)&w8[4] = *(const float4*)(wp + 4);
            float bsc = p.b_score[0];
            float acc8[8] = {0.f,0.f,0.f,0.f,0.f,0.f,0.f,0.f};
            float dsum = 0.f;
            if (p.useEncB) {
                const ushort_t* ecb = p.ec    + (size_t)b * T_FRAMES * H_DIM;
                const ushort_t* evb = p.encBt + (size_t)b * T_FRAMES * E_DIM;
                for (int t = tA; t < tEnd; t += 2) {
                    int tb = (t + 1 < tEnd) ? (t + 1) : t;
                    ushort8_t e8a = *(const ushort8_t*)(ecb + (size_t)t  * H_DIM + lane * 8);
                    ushort8_t e8b = *(const ushort8_t*)(ecb + (size_t)tb * H_DIM + lane * 8);
                    ushort8_t v8a = *(const ushort8_t*)(evb + (size_t)t  * E_DIM + lane * 8);
                    ushort8_t v8b = *(const ushort8_t*)(evb + (size_t)tb * E_DIM + lane * 8);
                    float ss[2] = {0.f, 0.f};
                    #pragma unroll
                    for (int j = 0; j < 8; ++j) {
                        ss[0] = fmaf(tanh_f(bf2f(e8a[j]) + rec8[j]), w8[j], ss[0]);
                        ss[1] = fmaf(tanh_f(bf2f(e8b[j]) + rec8[j]), w8[j], ss[1]);
                    }
                    wave_sum_n<2>(ss);
                    float pv0 = __expf(ss[0] + bsc);
                    float pv1 = (tb != t) ? __expf(ss[1] + bsc) : 0.f;
                    dsum += pv0 + pv1;
                    #pragma unroll
                    for (int j = 0; j < 8; ++j)
                        acc8[j] += pv0 * bf2f(v8a[j]) + pv1 * bf2f(v8b[j]);
                }
            } else {
                const ushort_t* ecb = p.ec + (size_t)b * T_FRAMES * H_DIM;
                for (int t = tA; t < tEnd; ++t) {
                    ushort8_t e8 = *(const ushort8_t*)(ecb + (size_t)t * H_DIM + lane * 8);
                    float ss = 0.f;
                    #pragma unroll
                    for (int j = 0; j < 8; ++j)
                        ss = fmaf(tanh_f(bf2f(e8[j]) + rec8[j]), w8[j], ss);
                    ss = wave_sum(ss) + bsc;
                    float pv = __expf(ss);
                    dsum += pv;
                    const float* vp = p.encoded + ((size_t)t * B_BATCH + b) * E_DIM + lane * 8;
                    float v8[8];
                    *(float4*)&v8[0] = *(const float4*)(vp);
                    *(float4*)&v8[4] = *(const float4*)(vp + 4);
                    #pragma unroll
                    for (int j = 0; j < 8; ++j)
                        acc8[j] = fmaf(pv, v8[j], acc8[j]);
                }
            }
            *(float4*)&sctx[wsub][lane * 8]     = *(float4*)&acc8[0];
            *(float4*)&sctx[wsub][lane * 8 + 4] = *(float4*)&acc8[4];
            if (lane == 0) sred[wsub] = dsum;
            __syncthreads();
            if (tid < E_DIM) {
                float csum = 0.f;
                #pragma unroll
                for (int w = 0; w < 16; ++w) csum += sctx[w][tid];
                p.ctxPart[((size_t)b * NSLICE + s) * E_DIM + tid] = csum;
            }
            if (tid == 0) {
                float d = 0.f;
                #pragma unroll
                for (int w = 0; w < 16; ++w) d += sred[w];
                p.denomPart[b * NSLICE + s] = d;
            }
        }
        group_barrier(p.flags, b, s, 3 * l + 2, tid);

        // ---- phase B: assemble context, GRU layer 0 for h-slice s ----
        {
            if (tid < NSLICE) sred[tid] = p.denomPart[b * NSLICE + tid];
            float csum = 0.f;
            if (tid < E_DIM) {
                #pragma unroll
                for (int s2 = 0; s2 < NSLICE; ++s2)
                    csum += p.ctxPart[((size_t)b * NSLICE + s2) * E_DIM + tid];
            }
            __syncthreads();
            float den = 0.f;
            #pragma unroll
            for (int s2 = 0; s2 < NSLICE; ++s2) den += sred[s2];
            float inv = __builtin_amdgcn_rcpf(den);
            if (tid < E_DIM) sctx[0][tid] = csum * inv;
            __syncthreads();

            int token = (l > 0) ? p.texts2[b * L_STEPS + l - 1] : -1;
            float x16[16];
            int k0 = lane * 16;
            if (k0 < H_DIM) {
                if (token >= 0) {
                    const float* ep = p.emb + (size_t)token * H_DIM + k0;
                    #pragma unroll
                    for (int q = 0; q < 4; ++q)
                        *(float4*)&x16[q * 4] = *(const float4*)(ep + q * 4);
                } else {
                    #pragma unroll
                    for (int j = 0; j < 16; ++j) x16[j] = 0.f;
                }
            } else {
                #pragma unroll
                for (int q = 0; q < 4; ++q)
                    *(float4*)&x16[q * 4] = *(const float4*)&sctx[0][k0 - H_DIM + q * 4];
            }
            float h8[8];
            const float* hp = h0cur + b * H_DIM + lane * 8;
            *(float4*)&h8[0] = *(const float4*)(hp);
            *(float4*)&h8[4] = *(const float4*)(hp + 4);
            const int IN = H_DIM + E_DIM;
            #pragma unroll
            for (int i = 0; i < 4; ++i) {
                int h = s * 64 + wsub * 4 + i;
                float v[6] = {0.f,0.f,0.f,0.f,0.f,0.f};
                #pragma unroll
                for (int g = 0; g < 3; ++g) {
                    const ushort_t* r = p.Wih0 + (size_t)(g * H_DIM + h) * IN + k0;
                    ushort8_t a = *(const ushort8_t*)(r);
                    ushort8_t c = *(const ushort8_t*)(r + 8);
                    #pragma unroll
                    for (int j = 0; j < 8; ++j) {
                        v[g] = fmaf(x16[j], bf2f(a[j]), v[g]);
                        v[g] = fmaf(x16[8 + j], bf2f(c[j]), v[g]);
                    }
                }
                #pragma unroll
                for (int g = 0; g < 3; ++g) {
                    const ushort_t* r = p.Whh0 + (size_t)(g * H_DIM + h) * H_DIM + lane * 8;
                    ushort8_t a = *(const ushort8_t*)(r);
                    #pragma unroll
                    for (int j = 0; j < 8; ++j)
                        v[3 + g] = fmaf(h8[j], bf2f(a[j]), v[3 + g]);
                }
                wave_sum_n<6>(v);
                if (lane == 0) {
                    float r = sigmoid_f(v[0] + p.b_ih0[h] + v[3] + p.b_hh0[h]);
                    float z = sigmoid_f(v[1] + p.b_ih0[H_DIM + h] + v[4] + p.b_hh0[H_DIM + h]);
                    float n = tanh_f(v[2] + p.b_ih0[2 * H_DIM + h] + r * (v[5] + p.b_hh0[2 * H_DIM + h]));
                    float hv = h0cur[b * H_DIM + h];
                    h0nxt[b * H_DIM + h] = (1.f - z) * n + z * hv;
                }
            }
        }
        group_barrier(p.flags, b, s, 3 * l + 3, tid);

        // ---- phase C: GRU layer 1 for h-slice s + next rec slice ----
        {
            float x8[8], g8[8];
            const float* xp = h0nxt + b * H_DIM + lane * 8;
            *(float4*)&x8[0] = *(const float4*)(xp);
            *(float4*)&x8[4] = *(const float4*)(xp + 4);
            const float* gp = h1cur + b * H_DIM + lane * 8;
            *(float4*)&g8[0] = *(const float4*)(gp);
            *(float4*)&g8[4] = *(const float4*)(gp + 4);
            #pragma unroll
            for (int i = 0; i < 4; ++i) {
                int h = s * 64 + wsub * 4 + i;
                float v[7] = {0.f,0.f,0.f,0.f,0.f,0.f,0.f};
                #pragma unroll
                for (int g = 0; g < 3; ++g) {
                    const ushort_t* r1 = p.Wih1 + (size_t)(g * H_DIM + h) * H_DIM + lane * 8;
                    ushort8_t a = *(const ushort8_t*)(r1);
                    const ushort_t* r2 = p.Whh1 + (size_t)(g * H_DIM + h) * H_DIM + lane * 8;
                    ushort8_t c = *(const ushort8_t*)(r2);
                    #pragma unroll
                    for (int j = 0; j < 8; ++j) {
                        v[g]     = fmaf(x8[j], bf2f(a[j]), v[g]);
                        v[3 + g] = fmaf(g8[j], bf2f(c[j]), v[3 + g]);
                    }
                }
                {
                    const ushort_t* r = p.Wrec + (size_t)h * H_DIM + lane * 8;
                    ushort8_t a = *(const ushort8_t*)(r);
                    #pragma unroll
                    for (int j = 0; j < 8; ++j)
                        v[6] = fmaf(x8[j], bf2f(a[j]), v[6]);
                }
                wave_sum_n<7>(v);
                if (lane == 0) {
                    float r = sigmoid_f(v[0] + p.b_ih1[h] + v[3] + p.b_hh1[h]);
                    float z = sigmoid_f(v[1] + p.b_ih1[H_DIM + h] + v[4] + p.b_hh1[H_DIM + h]);
                    float n = tanh_f(v[2] + p.b_ih1[2 * H_DIM + h] + r * (v[5] + p.b_hh1[2 * H_DIM + h]));
                    float hv = h1cur[b * H_DIM + h];
                    float out = (1.f - z) * n + z * hv;
                    h1nxt[b * H_DIM + h] = out;
                    p.outputs[((size_t)l * B_BATCH + b) * H_DIM + h] = out;
                    p.rec[b * H_DIM + h] = v[6];
                }
            }
        }
        group_barrier(p.flags, b, s, 3 * l + 4, tid);
    }
}

// ---------------- loss ----------------
__global__ __launch_bounds__(256) void loss_kernel(
    const float* __restrict__ outputs, const int* __restrict__ texts2,
    const float* __restrict__ W_out, const float* __restrict__ b_out,
    float* __restrict__ acc)
{
    int wid = threadIdx.x >> 6, lane = threadIdx.x & 63;
    int gw = blockIdx.x * 4 + wid;
    int nw = gridDim.x * 4;
    float lsum = 0.f, lcnt = 0.f;
    for (int r = gw; r < B_BATCH * L_STEPS; r += nw) {
        int b = r / L_STEPS, l = r % L_STEPS;
        int label = texts2[r];
        const float* orow = outputs + ((size_t)l * B_BATCH + b) * H_DIM;
        int k = lane * 8;
        float o8[8];
        *(float4*)&o8[0] = *(const float4*)(orow + k);
        *(float4*)&o8[4] = *(const float4*)(orow + k + 4);
        float m = -1e30f, se = 0.f, ll = 0.f;
        for (int c = 0; c < NCLS; ++c) {
            const float* wrow = W_out + (size_t)c * H_DIM + k;
            float p = 0.f;
            #pragma unroll
            for (int j = 0; j < 8; ++j) p = fmaf(o8[j], wrow[j], p);
            float logit = wave_sum(p) + b_out[c];
            if (c == label) ll = logit;
            if (logit > m) { se = se * expf(m - logit) + 1.f; m = logit; }
            else           { se += expf(logit - m); }
        }
        float lse = m + logf(se);
        if (label != 0) { lsum += lse - ll; lcnt += 1.f; }
    }
    if (lane == 0) { atomicAdd(&acc[0], lsum); atomicAdd(&acc[1], lcnt); }
}

__global__ void finalize_kernel(const float* __restrict__ acc, float* __restrict__ out) {
    out[0] = acc[0] / fmaxf(acc[1], 1.0f);
}

// ---------------- launch ----------------
static inline size_t align256(size_t x) { return (x + 255) & ~(size_t)255; }

extern "C" void kernel_launch(void* const* d_in, const int* in_sizes, int n_in,
                              void* d_out, int out_size, void* d_ws, size_t ws_size,
                              hipStream_t stream) {
    (void)in_sizes; (void)n_in; (void)out_size;
    const float* encoded      = (const float*)d_in[0];
    const int*   encoded_lens = (const int*)d_in[1];
    const int*   texts        = (const int*)d_in[2];
    const int*   text_lens    = (const int*)d_in[3];
    const float* W_enc        = (const float*)d_in[4];
    const float* b_enc        = (const float*)d_in[5];
    const float* W_rec        = (const float*)d_in[6];
    const float* w_score      = (const float*)d_in[7];
    const float* b_score      = (const float*)d_in[8];
    const float* emb          = (const float*)d_in[9];
    const float* W_ih0        = (const float*)d_in[10];
    const float* W_hh0        = (const float*)d_in[11];
    const float* b_ih0        = (const float*)d_in[12];
    const float* b_hh0        = (const float*)d_in[13];
    const float* W_ih1        = (const float*)d_in[14];
    const float* W_hh1        = (const float*)d_in[15];
    const float* b_ih1        = (const float*)d_in[16];
    const float* b_hh1        = (const float*)d_in[17];
    const float* W_out        = (const float*)d_in[18];
    const float* b_out        = (const float*)d_in[19];
    const float* h0p          = (const float*)d_in[20];

    char* ws = (char*)d_ws;
    size_t off = 0;
    ushort_t* ec     = (ushort_t*)(ws + off); off = align256(off + (size_t)T_FRAMES * B_BATCH * H_DIM * 2);
    ushort_t* Wrecb  = (ushort_t*)(ws + off); off = align256(off + (size_t)H_DIM * H_DIM * 2);
    ushort_t* Wih0b  = (ushort_t*)(ws + off); off = align256(off + (size_t)3 * H_DIM * (H_DIM + E_DIM) * 2);
    ushort_t* Whh0b  = (ushort_t*)(ws + off); off = align256(off + (size_t)3 * H_DIM * H_DIM * 2);
    ushort_t* Wih1b  = (ushort_t*)(ws + off); off = align256(off + (size_t)3 * H_DIM * H_DIM * 2);
    ushort_t* Whh1b  = (ushort_t*)(ws + off); off = align256(off + (size_t)3 * H_DIM * H_DIM * 2);
    float* rec       = (float*)(ws + off); off = align256(off + (size_t)B_BATCH * H_DIM * 4);
    float* ctxPart   = (float*)(ws + off); off = align256(off + (size_t)B_BATCH * NSLICE * E_DIM * 4);
    float* denomPart = (float*)(ws + off); off = align256(off + (size_t)B_BATCH * NSLICE * 4);
    float* h0a       = (float*)(ws + off); off = align256(off + (size_t)B_BATCH * H_DIM * 4);
    float* h0b       = (float*)(ws + off); off = align256(off + (size_t)B_BATCH * H_DIM * 4);
    float* h1a       = (float*)(ws + off); off = align256(off + (size_t)B_BATCH * H_DIM * 4);
    float* h1b       = (float*)(ws + off); off = align256(off + (size_t)B_BATCH * H_DIM * 4);
    float* outputs   = (float*)(ws + off); off = align256(off + (size_t)L_STEPS * B_BATCH * H_DIM * 4);
    int*   texts2    = (int*)(ws + off); off = align256(off + (size_t)B_BATCH * L_STEPS * 4);
    float* acc       = (float*)(ws + off); off = align256(off + 256);
    int*   flags     = (int*)(ws + off); off = align256(off + (size_t)B_BATCH * NSLICE * 32 * 4);
    size_t encB_off  = off;
    size_t encB_bytes = (size_t)T_FRAMES * B_BATCH * E_DIM * 2;
    int useEncB = (encB_off + encB_bytes <= ws_size) ? 1 : 0;
    ushort_t* encBt = (ushort_t*)(ws + encB_off);

    init_kernel<<<64, 256, 0, stream>>>(texts, text_lens, h0p, texts2, h0a, h1a, acc, flags);
    cvt_kernel<<<(H_DIM * H_DIM) / (256 * 8), 256, 0, stream>>>(W_rec, Wrecb, H_DIM * H_DIM);
    cvt_kernel<<<(3 * H_DIM * (H_DIM + E_DIM)) / (256 * 8), 256, 0, stream>>>(W_ih0, Wih0b, 3 * H_DIM * (H_DIM + E_DIM));
    cvt_kernel<<<(3 * H_DIM * H_DIM) / (256 * 8), 256, 0, stream>>>(W_hh0, Whh0b, 3 * H_DIM * H_DIM);
    cvt_kernel<<<(3 * H_DIM * H_DIM) / (256 * 8), 256, 0, stream>>>(W_ih1, Wih1b, 3 * H_DIM * H_DIM);
    cvt_kernel<<<(3 * H_DIM * H_DIM) / (256 * 8), 256, 0, stream>>>(W_hh1, Whh1b, 3 * H_DIM * H_DIM);
    if (useEncB) {
        cvt_transpose_kernel<<<T_FRAMES * B_BATCH, 64, 0, stream>>>(encoded, encBt);
    }
    enc_gemm_kernel<<<dim3(H_DIM / GTN, (T_FRAMES * B_BATCH) / GTM), 256, 0, stream>>>(
        encoded, W_enc, b_enc, ec);

    Params prm;
    prm.encoded = encoded; prm.lens = encoded_lens; prm.emb = emb;
    prm.w_score = w_score; prm.b_score = b_score;
    prm.b_ih0 = b_ih0; prm.b_hh0 = b_hh0; prm.b_ih1 = b_ih1; prm.b_hh1 = b_hh1;
    prm.ec = ec; prm.encBt = encBt;
    prm.Wrec = Wrecb; prm.Wih0 = Wih0b; prm.Whh0 = Whh0b; prm.Wih1 = Wih1b; prm.Whh1 = Whh1b;
    prm.rec = rec; prm.ctxPart = ctxPart; prm.denomPart = denomPart;
    prm.h0a = h0a; prm.h0b = h0b; prm.h1a = h1a; prm.h1b = h1b;
    prm.outputs = outputs; prm.texts2 = texts2; prm.flags = flags;
    prm.useEncB = useEncB;

    // cooperative launch only to guarantee co-residency of all 256 blocks;
    // synchronization is the custom per-group barrier (never grid.sync).
    void* args[] = { &prm };
    hipLaunchCooperativeKernel((const void*)decoder_kernel, dim3(NBLK), dim3(NTHR),
                               args, 0, stream);

    loss_kernel<<<64, 256, 0, stream>>>(outputs, texts2, W_out, b_out, acc);
    finalize_kernel<<<1, 1, 0, stream>>>(acc, (float*)d_out);
}

// Round 5
// 8735.551 us; speedup vs baseline: 5.1843x; 5.1843x over previous
//
#include <hip/hip_runtime.h>
#include <hip/hip_cooperative_groups.h>
#include <stdint.h>

#define T_FRAMES 1500
#define B_BATCH  32
#define E_DIM    512
#define H_DIM    512
#define NCLS     31
#define L_STEPS  101
#define EOS_TOK  30
#define NBLK     256
#define NTHR     1024
#define NSLICE   8

typedef unsigned short ushort_t;
typedef ushort_t ushort8_t __attribute__((ext_vector_type(8)));
typedef unsigned char uchar8_t __attribute__((ext_vector_type(8)));

__device__ __forceinline__ float bf2f(ushort_t u) {
    union { unsigned int i; float f; } v; v.i = ((unsigned int)u) << 16; return v.f;
}
__device__ __forceinline__ ushort_t f2bf(float f) {
    union { float f; unsigned int i; } v; v.f = f;
    unsigned int r = v.i + 0x7FFFu + ((v.i >> 16) & 1u);
    return (ushort_t)(r >> 16);
}
// fp8 e4m3fn decode: value = 2^(e-7)*(1+m/8), subnormal m*2^-9
__device__ __forceinline__ float fp8tof(unsigned int u) {
    unsigned int e = (u >> 3) & 15u, m = u & 7u, sg = (u >> 7) & 1u;
    union { unsigned int i; float f; } v;
    v.i = (sg << 31) | ((e + 120u) << 23) | (m << 20);
    float sub = (float)(int)m * 0.001953125f;
    sub = sg ? -sub : sub;
    return e ? v.f : sub;
}
__device__ __forceinline__ unsigned char f2fp8(float x) {
    unsigned char sg = (x < 0.f) ? 0x80 : 0;
    float a = fabsf(x);
    if (!(a == a)) return (unsigned char)(sg | 0x7E);
    if (a >= 448.f) return (unsigned char)(sg | 0x7E);
    if (a < 0.015625f) {
        int m = (int)rintf(a * 512.f);
        if (m >= 8) return (unsigned char)(sg | 0x08);
        return (unsigned char)(sg | m);
    }
    union { float f; unsigned int i; } v; v.f = a;
    unsigned int r = v.i + 0x7FFFFu + ((v.i >> 20) & 1u);
    unsigned int e = (r >> 23) - 127u + 7u;
    unsigned int m = (r >> 20) & 7u;
    if (e > 15u || (e == 15u && m == 7u)) { e = 15u; m = 6u; }
    return (unsigned char)(sg | (e << 3) | m);
}
__device__ __forceinline__ float wave_sum(float v) {
    #pragma unroll
    for (int o = 32; o > 0; o >>= 1) v += __shfl_xor(v, o, 64);
    return v;
}
template<int N>
__device__ __forceinline__ void wave_sum_n(float* v) {
    #pragma unroll
    for (int o = 32; o > 0; o >>= 1) {
        #pragma unroll
        for (int i = 0; i < N; ++i) v[i] += __shfl_xor(v[i], o, 64);
    }
}
__device__ __forceinline__ float tanh_f(float x) {
    float e = __expf(2.0f * x);
    return 1.0f - 2.0f * __builtin_amdgcn_rcpf(e + 1.0f);
}
__device__ __forceinline__ float sigmoid_f(float x) {
    return __builtin_amdgcn_rcpf(1.0f + __expf(-x));
}

// bypass (L2-skipping, device-coherent) accessors for the small shared state
__device__ __forceinline__ float ld_byp(const float* p) {
    return __hip_atomic_load(p, __ATOMIC_RELAXED, __HIP_MEMORY_SCOPE_AGENT);
}
__device__ __forceinline__ void st_byp(float* p, float v) {
    __hip_atomic_store(p, v, __ATOMIC_RELAXED, __HIP_MEMORY_SCOPE_AGENT);
}

// fence-free group barrier. No threadfence / release anywhere:
// data moves via sc1-bypass atomics; __syncthreads drains vmcnt (stores acked
// at device coherence point) before the flag store.
__device__ __forceinline__ void ffbarrier(int* flags, int base, int s, int k, int tid) {
    __syncthreads();                 // drains vmcnt -> prior bypass stores acked
    if (tid == 0)
        __hip_atomic_store(&flags[(base + s) * 32], k,
                           __ATOMIC_RELAXED, __HIP_MEMORY_SCOPE_AGENT);
    if (tid < NSLICE) {
        while (__hip_atomic_load(&flags[(base + tid) * 32],
                                 __ATOMIC_RELAXED, __HIP_MEMORY_SCOPE_AGENT) < k)
            __builtin_amdgcn_s_sleep(1);
    }
    __syncthreads();
    asm volatile("" ::: "memory");
}

// ---------------- init ----------------
__global__ __launch_bounds__(256) void init_kernel(
    const int* __restrict__ texts, const int* __restrict__ text_lens,
    const float* __restrict__ h0p,
    int* __restrict__ texts2, float* __restrict__ h0buf, float* __restrict__ h1buf,
    float* __restrict__ acc, int* __restrict__ flags)
{
    int idx = blockIdx.x * 256 + threadIdx.x;
    if (idx < 2) acc[idx] = 0.f;
    if (idx < B_BATCH * NSLICE * 32) flags[idx] = 0;
    if (idx < B_BATCH * L_STEPS) {
        int b = idx / L_STEPS, j = idx % L_STEPS;
        int v = (j < 100) ? texts[b * 100 + j] : 0;
        if (j == text_lens[b]) v = EOS_TOK;
        texts2[idx] = v;
    }
    for (int i = idx; i < B_BATCH * H_DIM; i += gridDim.x * 256) {
        h0buf[i] = h0p[i & (H_DIM - 1)];
        h1buf[i] = h0p[H_DIM + (i & (H_DIM - 1))];
    }
}

// ---------------- one-time f32 -> bf16 convert ----------------
__global__ __launch_bounds__(256) void cvt_kernel(const float* __restrict__ in,
                                                  ushort_t* __restrict__ out, int n) {
    int i = (blockIdx.x * 256 + threadIdx.x) * 8;
    if (i >= n) return;
    float4 a = *(const float4*)(in + i);
    float4 b = *(const float4*)(in + i + 4);
    ushort8_t o;
    o[0] = f2bf(a.x); o[1] = f2bf(a.y); o[2] = f2bf(a.z); o[3] = f2bf(a.w);
    o[4] = f2bf(b.x); o[5] = f2bf(b.y); o[6] = f2bf(b.z); o[7] = f2bf(b.w);
    *(ushort8_t*)(out + i) = o;
}

// ---------------- encoded [t][b][e] f32 -> [b][t][e] fp8 ----------------
__global__ __launch_bounds__(64) void cvt_fp8_transpose_kernel(const float* __restrict__ in,
                                                               unsigned char* __restrict__ out) {
    int row = blockIdx.x;                 // t*32+b
    int t = row >> 5, b = row & 31;
    int k = threadIdx.x * 8;
    const float* ip = in + (size_t)row * E_DIM + k;
    float4 a = *(const float4*)(ip);
    float4 c = *(const float4*)(ip + 4);
    float vals[8] = {a.x, a.y, a.z, a.w, c.x, c.y, c.z, c.w};
    uchar8_t o;
    #pragma unroll
    for (int j = 0; j < 8; ++j) o[j] = f2fp8(vals[j]);
    *(uchar8_t*)(out + ((size_t)b * T_FRAMES + t) * E_DIM + k) = o;
}

// ---------------- enc_contrib GEMM (f32 in, bf16 out, batch-major C) ----------------
#define GTM 128
#define GTN 128
#define GTK 32
#define GLDA (GTM + 4)

__global__ __launch_bounds__(256) void enc_gemm_kernel(
    const float* __restrict__ A, const float* __restrict__ W,
    const float* __restrict__ bias, ushort_t* __restrict__ C)
{
    __shared__ float As[GTK][GLDA];
    __shared__ float Bs[GTK][GLDA];
    const int m0 = blockIdx.y * GTM;
    const int n0 = blockIdx.x * GTN;
    const int tid = threadIdx.x;
    const int tx = tid & 15, ty = tid >> 4;
    const int lr = tid >> 3;
    const int lc = (tid & 7) << 2;
    float acc[8][8] = {};
    for (int k0 = 0; k0 < E_DIM; k0 += GTK) {
        #pragma unroll
        for (int p = 0; p < 4; ++p) {
            float4 a = *(const float4*)(A + (size_t)(m0 + lr + 32 * p) * E_DIM + k0 + lc);
            As[lc + 0][lr + 32 * p] = a.x; As[lc + 1][lr + 32 * p] = a.y;
            As[lc + 2][lr + 32 * p] = a.z; As[lc + 3][lr + 32 * p] = a.w;
            float4 b = *(const float4*)(W + (size_t)(n0 + lr + 32 * p) * E_DIM + k0 + lc);
            Bs[lc + 0][lr + 32 * p] = b.x; Bs[lc + 1][lr + 32 * p] = b.y;
            Bs[lc + 2][lr + 32 * p] = b.z; Bs[lc + 3][lr + 32 * p] = b.w;
        }
        __syncthreads();
        #pragma unroll
        for (int k = 0; k < GTK; ++k) {
            float av[8], bv[8];
            *(float4*)&av[0] = *(const float4*)&As[k][ty * 8];
            *(float4*)&av[4] = *(const float4*)&As[k][ty * 8 + 4];
            *(float4*)&bv[0] = *(const float4*)&Bs[k][tx * 8];
            *(float4*)&bv[4] = *(const float4*)&Bs[k][tx * 8 + 4];
            #pragma unroll
            for (int i = 0; i < 8; ++i)
                #pragma unroll
                for (int j = 0; j < 8; ++j)
                    acc[i][j] = fmaf(av[i], bv[j], acc[i][j]);
        }
        __syncthreads();
    }
    const float* bp = bias + n0 + tx * 8;
    #pragma unroll
    for (int i = 0; i < 8; ++i) {
        int m = m0 + ty * 8 + i;
        int b = m & 31, t = m >> 5;       // A rows are t*32+b
        ushort8_t o;
        #pragma unroll
        for (int j = 0; j < 8; ++j) o[j] = f2bf(acc[i][j] + bp[j]);
        *(ushort8_t*)(C + ((size_t)b * T_FRAMES + t) * H_DIM + n0 + tx * 8) = o;
    }
}

// ---------------- persistent decoder ----------------
struct Params {
    const float* encoded; const int* lens; const float* emb;
    const float* w_score; const float* b_score;
    const float* b_ih0; const float* b_hh0; const float* b_ih1; const float* b_hh1;
    const ushort_t* ec; const unsigned char* encF8;
    const ushort_t* Wrec; const ushort_t* Wih0; const ushort_t* Whh0;
    const ushort_t* Wih1; const ushort_t* Whh1;
    float* rec; float* ctxPart; float* denomPart;
    float* h0a; float* h0b; float* h1a; float* h1b;
    float* outputs; const int* texts2; int* flags;
    int useEncB;
};

__global__ __launch_bounds__(NTHR, 1) void decoder_kernel(Params p) {
    const int tid = threadIdx.x;          // 0..1023
    const int bid = blockIdx.x;           // 0..255
    const int lane = tid & 63;
    const int wsub = tid >> 6;            // 0..15
    const int b = bid >> 3;               // batch
    const int s = bid & 7;                // slice -> XCD s (round-robin)
    const int fbase = b * NSLICE;
    __shared__ float sctx[16][E_DIM];     // 32 KB; rows 0/1 double as staging
    __shared__ float sred[16];
    float* sA = &sctx[0][0];
    float* sB = &sctx[1][0];

    // ---- initial rec slice from h0a (h0a from init kernel: normal loads ok) ----
    {
        const float* xp = p.h0a + b * H_DIM + lane * 8;
        float x8[8];
        *(float4*)&x8[0] = *(const float4*)(xp);
        *(float4*)&x8[4] = *(const float4*)(xp + 4);
        #pragma unroll
        for (int i = 0; i < 4; ++i) {
            int h = s * 64 + wsub * 4 + i;
            ushort8_t w8 = *(const ushort8_t*)(p.Wrec + (size_t)h * H_DIM + lane * 8);
            float v = 0.f;
            #pragma unroll
            for (int j = 0; j < 8; ++j) v = fmaf(x8[j], bf2f(w8[j]), v);
            v = wave_sum(v);
            if (lane == 0) st_byp(&p.rec[b * H_DIM + h], v);
        }
    }
    ffbarrier(p.flags, fbase, s, 1, tid);

    const int len = p.lens[b];
    for (int l = 0; l < L_STEPS; ++l) {
        float* h0cur = (l & 1) ? p.h0b : p.h0a;
        float* h0nxt = (l & 1) ? p.h0a : p.h0b;
        float* h1cur = (l & 1) ? p.h1b : p.h1a;
        float* h1nxt = (l & 1) ? p.h1a : p.h1b;

        // ---- phase A: scores + exp + context/denom partials, t interleaved ----
        {
            for (int i = tid; i < H_DIM; i += NTHR)
                sA[i] = ld_byp(&p.rec[b * H_DIM + i]);
            __syncthreads();
            float rec8[8], w8[8];
            #pragma unroll
            for (int j = 0; j < 8; ++j) rec8[j] = sA[lane * 8 + j];
            const float* wp = p.w_score + lane * 8;
            *(float4*)&w8[0] = *(const float4*)(wp);
            *(float4*)&w8[4] = *(const float4*)(wp + 4);
            float bsc = p.b_score[0];
            __syncthreads();                 // everyone has rec8 before sctx reuse
            float acc8[8] = {0.f,0.f,0.f,0.f,0.f,0.f,0.f,0.f};
            float dsum = 0.f;
            const int gw = wsub * NSLICE + s;   // 0..127, balanced across slices
            if (p.useEncB) {
                const ushort_t* ecb = p.ec + (size_t)b * T_FRAMES * H_DIM + lane * 8;
                const unsigned char* efb = p.encF8 + (size_t)b * T_FRAMES * E_DIM + lane * 8;
                for (int t = gw; t < len; t += 256) {
                    int t2 = t + 128;
                    bool has2 = t2 < len;
                    int t2c = has2 ? t2 : t;
                    ushort8_t e8a = *(const ushort8_t*)(ecb + (size_t)t   * H_DIM);
                    ushort8_t e8b = *(const ushort8_t*)(ecb + (size_t)t2c * H_DIM);
                    uchar8_t v8a = *(const uchar8_t*)(efb + (size_t)t   * E_DIM);
                    uchar8_t v8b = *(const uchar8_t*)(efb + (size_t)t2c * E_DIM);
                    float ss[2] = {0.f, 0.f};
                    #pragma unroll
                    for (int j = 0; j < 8; ++j) {
                        ss[0] = fmaf(tanh_f(bf2f(e8a[j]) + rec8[j]), w8[j], ss[0]);
                        ss[1] = fmaf(tanh_f(bf2f(e8b[j]) + rec8[j]), w8[j], ss[1]);
                    }
                    wave_sum_n<2>(ss);
                    float pv0 = __expf(ss[0] + bsc);
                    float pv1 = has2 ? __expf(ss[1] + bsc) : 0.f;
                    dsum += pv0 + pv1;
                    #pragma unroll
                    for (int j = 0; j < 8; ++j)
                        acc8[j] += pv0 * fp8tof(v8a[j]) + pv1 * fp8tof(v8b[j]);
                }
            } else {
                const ushort_t* ecb = p.ec + (size_t)b * T_FRAMES * H_DIM + lane * 8;
                for (int t = gw; t < len; t += 128) {
                    ushort8_t e8 = *(const ushort8_t*)(ecb + (size_t)t * H_DIM);
                    float ss = 0.f;
                    #pragma unroll
                    for (int j = 0; j < 8; ++j)
                        ss = fmaf(tanh_f(bf2f(e8[j]) + rec8[j]), w8[j], ss);
                    ss = wave_sum(ss) + bsc;
                    float pv = __expf(ss);
                    dsum += pv;
                    const float* vp = p.encoded + ((size_t)t * B_BATCH + b) * E_DIM + lane * 8;
                    float v8[8];
                    *(float4*)&v8[0] = *(const float4*)(vp);
                    *(float4*)&v8[4] = *(const float4*)(vp + 4);
                    #pragma unroll
                    for (int j = 0; j < 8; ++j)
                        acc8[j] = fmaf(pv, v8[j], acc8[j]);
                }
            }
            *(float4*)&sctx[wsub][lane * 8]     = *(float4*)&acc8[0];
            *(float4*)&sctx[wsub][lane * 8 + 4] = *(float4*)&acc8[4];
            if (lane == 0) sred[wsub] = dsum;
            __syncthreads();
            if (tid < E_DIM) {
                float csum = 0.f;
                #pragma unroll
                for (int w = 0; w < 16; ++w) csum += sctx[w][tid];
                st_byp(&p.ctxPart[((size_t)b * NSLICE + s) * E_DIM + tid], csum);
            }
            if (tid == 0) {
                float d = 0.f;
                #pragma unroll
                for (int w = 0; w < 16; ++w) d += sred[w];
                st_byp(&p.denomPart[b * NSLICE + s], d);
            }
        }
        ffbarrier(p.flags, fbase, s, 3 * l + 2, tid);

        // ---- phase B: assemble context + GRU layer 0 (h-slice s) ----
        {
            if (tid < E_DIM) {
                float c = 0.f;
                #pragma unroll
                for (int s2 = 0; s2 < NSLICE; ++s2)
                    c += ld_byp(&p.ctxPart[((size_t)b * NSLICE + s2) * E_DIM + tid]);
                sA[tid] = c;
                sB[tid] = ld_byp(&h0cur[b * H_DIM + tid]);
            } else if (tid < E_DIM + NSLICE) {
                sred[tid - E_DIM] = ld_byp(&p.denomPart[b * NSLICE + (tid - E_DIM)]);
            }
            __syncthreads();
            float den = sred[0] + sred[1] + sred[2] + sred[3]
                      + sred[4] + sred[5] + sred[6] + sred[7];
            float inv = __builtin_amdgcn_rcpf(den);
            int token = (l > 0) ? p.texts2[b * L_STEPS + l - 1] : -1;
            float x16[16];
            int k0 = lane * 16;
            if (k0 < H_DIM) {
                if (token >= 0) {
                    const float* ep = p.emb + (size_t)token * H_DIM + k0;
                    #pragma unroll
                    for (int q = 0; q < 4; ++q)
                        *(float4*)&x16[q * 4] = *(const float4*)(ep + q * 4);
                } else {
                    #pragma unroll
                    for (int j = 0; j < 16; ++j) x16[j] = 0.f;
                }
            } else {
                #pragma unroll
                for (int j = 0; j < 16; ++j) x16[j] = sA[k0 - H_DIM + j] * inv;
            }
            float h8[8];
            #pragma unroll
            for (int j = 0; j < 8; ++j) h8[j] = sB[lane * 8 + j];
            const int IN = H_DIM + E_DIM;
            #pragma unroll
            for (int i = 0; i < 4; ++i) {
                int h = s * 64 + wsub * 4 + i;
                float v[6] = {0.f,0.f,0.f,0.f,0.f,0.f};
                #pragma unroll
                for (int g = 0; g < 3; ++g) {
                    const ushort_t* r = p.Wih0 + (size_t)(g * H_DIM + h) * IN + k0;
                    ushort8_t a = *(const ushort8_t*)(r);
                    ushort8_t c = *(const ushort8_t*)(r + 8);
                    #pragma unroll
                    for (int j = 0; j < 8; ++j) {
                        v[g] = fmaf(x16[j], bf2f(a[j]), v[g]);
                        v[g] = fmaf(x16[8 + j], bf2f(c[j]), v[g]);
                    }
                }
                #pragma unroll
                for (int g = 0; g < 3; ++g) {
                    const ushort_t* r = p.Whh0 + (size_t)(g * H_DIM + h) * H_DIM + lane * 8;
                    ushort8_t a = *(const ushort8_t*)(r);
                    #pragma unroll
                    for (int j = 0; j < 8; ++j)
                        v[3 + g] = fmaf(h8[j], bf2f(a[j]), v[3 + g]);
                }
                wave_sum_n<6>(v);
                if (lane == 0) {
                    float r = sigmoid_f(v[0] + p.b_ih0[h] + v[3] + p.b_hh0[h]);
                    float z = sigmoid_f(v[1] + p.b_ih0[H_DIM + h] + v[4] + p.b_hh0[H_DIM + h]);
                    float n = tanh_f(v[2] + p.b_ih0[2 * H_DIM + h] + r * (v[5] + p.b_hh0[2 * H_DIM + h]));
                    float hv = sB[h];
                    st_byp(&h0nxt[b * H_DIM + h], (1.f - z) * n + z * hv);
                }
            }
        }
        ffbarrier(p.flags, fbase, s, 3 * l + 3, tid);

        // ---- phase C: GRU layer 1 (h-slice s) + next rec slice ----
        {
            if (tid < E_DIM) {
                sA[tid] = ld_byp(&h0nxt[b * H_DIM + tid]);
                sB[tid] = ld_byp(&h1cur[b * H_DIM + tid]);
            }
            __syncthreads();
            float x8[8], g8[8];
            #pragma unroll
            for (int j = 0; j < 8; ++j) { x8[j] = sA[lane * 8 + j]; g8[j] = sB[lane * 8 + j]; }
            #pragma unroll
            for (int i = 0; i < 4; ++i) {
                int h = s * 64 + wsub * 4 + i;
                float v[7] = {0.f,0.f,0.f,0.f,0.f,0.f,0.f};
                #pragma unroll
                for (int g = 0; g < 3; ++g) {
                    const ushort_t* r1 = p.Wih1 + (size_t)(g * H_DIM + h) * H_DIM + lane * 8;
                    ushort8_t a = *(const ushort8_t*)(r1);
                    const ushort_t* r2 = p.Whh1 + (size_t)(g * H_DIM + h) * H_DIM + lane * 8;
                    ushort8_t c = *(const ushort8_t*)(r2);
                    #pragma unroll
                    for (int j = 0; j < 8; ++j) {
                        v[g]     = fmaf(x8[j], bf2f(a[j]), v[g]);
                        v[3 + g] = fmaf(g8[j], bf2f(c[j]), v[3 + g]);
                    }
                }
                {
                    const ushort_t* r = p.Wrec + (size_t)h * H_DIM + lane * 8;
                    ushort8_t a = *(const ushort8_t*)(r);
                    #pragma unroll
                    for (int j = 0; j < 8; ++j)
                        v[6] = fmaf(x8[j], bf2f(a[j]), v[6]);
                }
                wave_sum_n<7>(v);
                if (lane == 0) {
                    float r = sigmoid_f(v[0] + p.b_ih1[h] + v[3] + p.b_hh1[h]);
                    float z = sigmoid_f(v[1] + p.b_ih1[H_DIM + h] + v[4] + p.b_hh1[H_DIM + h]);
                    float n = tanh_f(v[2] + p.b_ih1[2 * H_DIM + h] + r * (v[5] + p.b_hh1[2 * H_DIM + h]));
                    float hv = sB[h];
                    float out = (1.f - z) * n + z * hv;
                    st_byp(&h1nxt[b * H_DIM + h], out);
                    p.outputs[((size_t)l * B_BATCH + b) * H_DIM + h] = out;  // read after kernel end
                    st_byp(&p.rec[b * H_DIM + h], v[6]);
                }
            }
        }
        ffbarrier(p.flags, fbase, s, 3 * l + 4, tid);
    }
}

// ---------------- loss ----------------
__global__ __launch_bounds__(256) void loss_kernel(
    const float* __restrict__ outputs, const int* __restrict__ texts2,
    const float* __restrict__ W_out, const float* __restrict__ b_out,
    float* __restrict__ acc)
{
    int wid = threadIdx.x >> 6, lane = threadIdx.x & 63;
    int gw = blockIdx.x * 4 + wid;
    int nw = gridDim.x * 4;
    float lsum = 0.f, lcnt = 0.f;
    for (int r = gw; r < B_BATCH * L_STEPS; r += nw) {
        int b = r / L_STEPS, l = r % L_STEPS;
        int label = texts2[r];
        const float* orow = outputs + ((size_t)l * B_BATCH + b) * H_DIM;
        int k = lane * 8;
        float o8[8];
        *(float4*)&o8[0] = *(const float4*)(orow + k);
        *(float4*)&o8[4] = *(const float4*)(orow + k + 4);
        float m = -1e30f, se = 0.f, ll = 0.f;
        for (int c = 0; c < NCLS; ++c) {
            const float* wrow = W_out + (size_t)c * H_DIM + k;
            float p = 0.f;
            #pragma unroll
            for (int j = 0; j < 8; ++j) p = fmaf(o8[j], wrow[j], p);
            float logit = wave_sum(p) + b_out[c];
            if (c == label) ll = logit;
            if (logit > m) { se = se * expf(m - logit) + 1.f; m = logit; }
            else           { se += expf(logit - m); }
        }
        float lse = m + logf(se);
        if (label != 0) { lsum += lse - ll; lcnt += 1.f; }
    }
    if (lane == 0) { atomicAdd(&acc[0], lsum); atomicAdd(&acc[1], lcnt); }
}

__global__ void finalize_kernel(const float* __restrict__ acc, float* __restrict__ out) {
    out[0] = acc[0] / fmaxf(acc[1], 1.0f);
}

// ---------------- launch ----------------
static inline size_t align256(size_t x) { return (x + 255) & ~(size_t)255; }

extern "C" void kernel_launch(void* const* d_in, const int* in_sizes, int n_in,
                              void* d_out, int out_size, void* d_ws, size_t ws_size,
                              hipStream_t stream) {
    (void)in_sizes; (void)n_in; (void)out_size;
    const float* encoded      = (const float*)d_in[0];
    const int*   encoded_lens = (const int*)d_in[1];
    const int*   texts        = (const int*)d_in[2];
    const int*   text_lens    = (const int*)d_in[3];
    const float* W_enc        = (const float*)d_in[4];
    const float* b_enc        = (const float*)d_in[5];
    const float* W_rec        = (const float*)d_in[6];
    const float* w_score      = (const float*)d_in[7];
    const float* b_score      = (const float*)d_in[8];
    const float* emb          = (const float*)d_in[9];
    const float* W_ih0        = (const float*)d_in[10];
    const float* W_hh0        = (const float*)d_in[11];
    const float* b_ih0        = (const float*)d_in[12];
    const float* b_hh0        = (const float*)d_in[13];
    const float* W_ih1        = (const float*)d_in[14];
    const float* W_hh1        = (const float*)d_in[15];
    const float* b_ih1        = (const float*)d_in[16];
    const float* b_hh1        = (const float*)d_in[17];
    const float* W_out        = (const float*)d_in[18];
    const float* b_out        = (const float*)d_in[19];
    const float* h0p          = (const float*)d_in[20];

    char* ws = (char*)d_ws;
    size_t off = 0;
    ushort_t* ec     = (ushort_t*)(ws + off); off = align256(off + (size_t)T_FRAMES * B_BATCH * H_DIM * 2);
    ushort_t* Wrecb  = (ushort_t*)(ws + off); off = align256(off + (size_t)H_DIM * H_DIM * 2);
    ushort_t* Wih0b  = (ushort_t*)(ws + off); off = align256(off + (size_t)3 * H_DIM * (H_DIM + E_DIM) * 2);
    ushort_t* Whh0b  = (ushort_t*)(ws + off); off = align256(off + (size_t)3 * H_DIM * H_DIM * 2);
    ushort_t* Wih1b  = (ushort_t*)(ws + off); off = align256(off + (size_t)3 * H_DIM * H_DIM * 2);
    ushort_t* Whh1b  = (ushort_t*)(ws + off); off = align256(off + (size_t)3 * H_DIM * H_DIM * 2);
    float* rec       = (float*)(ws + off); off = align256(off + (size_t)B_BATCH * H_DIM * 4);
    float* ctxPart   = (float*)(ws + off); off = align256(off + (size_t)B_BATCH * NSLICE * E_DIM * 4);
    float* denomPart = (float*)(ws + off); off = align256(off + (size_t)B_BATCH * NSLICE * 4);
    float* h0a       = (float*)(ws + off); off = align256(off + (size_t)B_BATCH * H_DIM * 4);
    float* h0b       = (float*)(ws + off); off = align256(off + (size_t)B_BATCH * H_DIM * 4);
    float* h1a       = (float*)(ws + off); off = align256(off + (size_t)B_BATCH * H_DIM * 4);
    float* h1b       = (float*)(ws + off); off = align256(off + (size_t)B_BATCH * H_DIM * 4);
    float* outputs   = (float*)(ws + off); off = align256(off + (size_t)L_STEPS * B_BATCH * H_DIM * 4);
    int*   texts2    = (int*)(ws + off); off = align256(off + (size_t)B_BATCH * L_STEPS * 4);
    float* acc       = (float*)(ws + off); off = align256(off + 256);
    int*   flags     = (int*)(ws + off); off = align256(off + (size_t)B_BATCH * NSLICE * 32 * 4);
    size_t encF8_off = off;
    size_t encF8_bytes = (size_t)T_FRAMES * B_BATCH * E_DIM;      // fp8: 24.6 MB
    int useEncB = (encF8_off + encF8_bytes <= ws_size) ? 1 : 0;
    unsigned char* encF8 = (unsigned char*)(ws + encF8_off);

    init_kernel<<<64, 256, 0, stream>>>(texts, text_lens, h0p, texts2, h0a, h1a, acc, flags);
    cvt_kernel<<<(H_DIM * H_DIM) / (256 * 8), 256, 0, stream>>>(W_rec, Wrecb, H_DIM * H_DIM);
    cvt_kernel<<<(3 * H_DIM * (H_DIM + E_DIM)) / (256 * 8), 256, 0, stream>>>(W_ih0, Wih0b, 3 * H_DIM * (H_DIM + E_DIM));
    cvt_kernel<<<(3 * H_DIM * H_DIM) / (256 * 8), 256, 0, stream>>>(W_hh0, Whh0b, 3 * H_DIM * H_DIM);
    cvt_kernel<<<(3 * H_DIM * H_DIM) / (256 * 8), 256, 0, stream>>>(W_ih1, Wih1b, 3 * H_DIM * H_DIM);
    cvt_kernel<<<(3 * H_DIM * H_DIM) / (256 * 8), 256, 0, stream>>>(W_hh1, Whh1b, 3 * H_DIM * H_DIM);
    if (useEncB) {
        cvt_fp8_transpose_kernel<<<T_FRAMES * B_BATCH, 64, 0, stream>>>(encoded, encF8);
    }
    enc_gemm_kernel<<<dim3(H_DIM / GTN, (T_FRAMES * B_BATCH) / GTM), 256, 0, stream>>>(
        encoded, W_enc, b_enc, ec);

    Params prm;
    prm.encoded = encoded; prm.lens = encoded_lens; prm.emb = emb;
    prm.w_score = w_score; prm.b_score = b_score;
    prm.b_ih0 = b_ih0; prm.b_hh0 = b_hh0; prm.b_ih1 = b_ih1; prm.b_hh1 = b_hh1;
    prm.ec = ec; prm.encF8 = encF8;
    prm.Wrec = Wrecb; prm.Wih0 = Wih0b; prm.Whh0 = Whh0b; prm.Wih1 = Wih1b; prm.Whh1 = Whh1b;
    prm.rec = rec; prm.ctxPart = ctxPart; prm.denomPart = denomPart;
    prm.h0a = h0a; prm.h0b = h0b; prm.h1a = h1a; prm.h1b = h1b;
    prm.outputs = outputs; prm.texts2 = texts2; prm.flags = flags;
    prm.useEncB = useEncB;

    void* args[] = { &prm };
    hipLaunchCooperativeKernel((const void*)decoder_kernel, dim3(NBLK), dim3(NTHR),
                               args, 0, stream);

    loss_kernel<<<64, 256, 0, stream>>>(outputs, texts2, W_out, b_out, acc);
    finalize_kernel<<<1, 1, 0, stream>>>(acc, (float*)d_out);
}